// Round 12
// baseline (581.809 us; speedup 1.0000x reference)
//
#include <hip/hip_runtime.h>

#define NN 100000     // nodes
#define NE 1600000    // edges
#define NGR 512       // graphs
#define KF 128        // IN_F == H1
#define H2F 256
#define NGRP 16
#define NFAM 10

#define CH 128                          // nodes per chunk
#define NCHUNK ((NN + CH - 1) / CH)     // 782
#define PT 6656                         // edges per partition tile (round-1 best)
#define NT ((NE + PT - 1) / PT)         // 241
#define PREPB_BLKS 64                   // 128*128/256
#define GBB ((NN + 255) / 256)          // 391 blocks: graph-boundary scan

#define NSL 4                           // feature slices (32 B each; 3.2 MB/slice < 4 MB L2/XCD)

typedef __attribute__((ext_vector_type(8))) short short8;
typedef __attribute__((ext_vector_type(4))) float floatx4;
typedef __attribute__((ext_vector_type(2))) float floatx2;

__device__ __forceinline__ unsigned short f2bf(float f) {
  unsigned u = __float_as_uint(f);
  unsigned r = (u + 0x7fff + ((u >> 16) & 1)) >> 16;
  return (unsigned short)r;
}
// fp8 e4m3 pair (features t, t+64) <-> floats via gfx950 HW converters
__device__ __forceinline__ unsigned short pk_fp8(float a, float b) {
  return (unsigned short)__builtin_amdgcn_cvt_pk_fp8_f32(a, b, 0, false);
}
__device__ __forceinline__ floatx2 unpk_fp8(unsigned short u) {
  return __builtin_amdgcn_cvt_pk_f32_fp8((int)u, false);
}

// ------- merged: per-tile chunk histogram -> tot | W1 swizzle | graph-boundary scan -------

__global__ __launch_bounds__(256) void k_histprep(const int* __restrict__ ei,
                                                  const int* __restrict__ batch,
                                                  int* __restrict__ tot,
                                                  int* __restrict__ gb,
                                                  const float* __restrict__ W,
                                                  unsigned short* __restrict__ Bp) {
  __shared__ int lh[NCHUNK];
  int tid = threadIdx.x;
  if (blockIdx.x >= NT + PREPB_BLKS) {  // graph-boundary scan
    int n = (blockIdx.x - NT - PREPB_BLKS) * 256 + tid;
    if (n >= NN) return;
    int b0 = batch[n];
    if (n == 0) {
      for (int g = 0; g <= b0; ++g) gb[g] = 0;
    }
    int b1 = (n + 1 < NN) ? batch[n + 1] : NGR;
    for (int g = b0 + 1; g <= b1; ++g) gb[g] = n + 1;
    return;
  }
  if (blockIdx.x >= NT) {  // W1 swizzle
    int idx = (blockIdx.x - NT) * 256 + tid;
    int j = idx & 7;
    int l = (idx >> 3) & 63;
    int rest = idx >> 9;
    int nc = rest & 7;
    int kc = rest >> 3;
    int k = kc * 32 + (l >> 4) * 8 + j;
    int nn = nc * 16 + (l & 15);
    Bp[idx] = f2bf(W[k * KF + nn]);
    return;
  }
  for (int g = tid; g < NCHUNK; g += 256) lh[g] = 0;
  __syncthreads();
  int base = blockIdx.x * PT;
  int nv = min(PT, NE - base);
  for (int i = tid; i < nv; i += 256) atomicAdd(&lh[ei[NE + base + i] >> 7], 1);
  __syncthreads();
  for (int g = tid; g < NCHUNK; g += 256) {
    int v = lh[g];
    if (v) atomicAdd(&tot[g], v);
  }
}

// ---------------- exclusive scan tot -> cbase; init cursor ----------------

__global__ __launch_bounds__(256) void k_scantot(const int* __restrict__ tot,
                                                 int* __restrict__ cbase,
                                                 int* __restrict__ cursor) {
  __shared__ int ssc[256];
  int tid = threadIdx.x;
  int v4[4]; int loc = 0;
#pragma unroll
  for (int j = 0; j < 4; ++j) {
    int idx = tid * 4 + j;
    v4[j] = (idx < NCHUNK) ? tot[idx] : 0;
    loc += v4[j];
  }
  ssc[tid] = loc;
  __syncthreads();
  for (int off = 1; off < 256; off <<= 1) {
    int val = (tid >= off) ? ssc[tid - off] : 0;
    __syncthreads();
    ssc[tid] += val;
    __syncthreads();
  }
  int excl = ssc[tid] - loc;
#pragma unroll
  for (int j = 0; j < 4; ++j) {
    int idx = tid * 4 + j;
    if (idx < NCHUNK) { cbase[idx] = excl; cursor[idx] = excl; }
    excl += v4[j];
  }
  if (tid == 255) cbase[NCHUNK] = excl;  // == NE
}

// ---------------- partition: LDS-staged, cursor-reserved per-chunk slices ----------------

__global__ __launch_bounds__(256) void k_pscatter(const int* __restrict__ ei,
                                                  int* __restrict__ cursor,
                                                  int2* __restrict__ erec) {
  __shared__ int2 stage[PT];
  __shared__ int lstart[NCHUNK];
  __shared__ int lrun[NCHUNK];
  __shared__ int gbase[NCHUNK];
  __shared__ int ssc[256];
  int t0 = blockIdx.x, tid = threadIdx.x;
  for (int g = tid; g < NCHUNK; g += 256) lrun[g] = 0;
  __syncthreads();
  int base = t0 * PT;
  int nv = min(PT, NE - base);
  for (int i = tid; i < nv; i += 256) atomicAdd(&lrun[ei[NE + base + i] >> 7], 1);
  __syncthreads();
  int v4[4]; int loc = 0;
#pragma unroll
  for (int j = 0; j < 4; ++j) {
    int idx = tid * 4 + j;
    v4[j] = (idx < NCHUNK) ? lrun[idx] : 0;
    loc += v4[j];
  }
  ssc[tid] = loc;
  __syncthreads();
  for (int off = 1; off < 256; off <<= 1) {
    int val = (tid >= off) ? ssc[tid - off] : 0;
    __syncthreads();
    ssc[tid] += val;
    __syncthreads();
  }
  int excl = ssc[tid] - loc;
#pragma unroll
  for (int j = 0; j < 4; ++j) {
    int idx = tid * 4 + j;
    if (idx < NCHUNK) lstart[idx] = excl;
    excl += v4[j];
  }
  __syncthreads();
  for (int g = tid; g < NCHUNK; g += 256) {
    int cnt = ((g + 1 < NCHUNK) ? lstart[g + 1] : nv) - lstart[g];
    gbase[g] = cnt ? atomicAdd(&cursor[g], cnt) : 0;
    lrun[g] = lstart[g];
  }
  __syncthreads();
  for (int i = tid; i < nv; i += 256) {
    int s = ei[base + i], d = ei[NE + base + i];
    int pos = atomicAdd(&lrun[d >> 7], 1);
    stage[pos] = make_int2(s, d);
  }
  __syncthreads();
  for (int j = tid; j < nv; j += 256) {
    int2 r = stage[j];
    int g = r.y >> 7;
    erec[gbase[g] + (j - lstart[g])] = r;
  }
}

// ---------------- per-chunk counting sort into packed per-node runs (+dinv) ----------------

__global__ __launch_bounds__(256) void k_sort(const int2* __restrict__ erec,
                                              const int* __restrict__ cbase,
                                              int* __restrict__ esrc,
                                              int* __restrict__ rowptr,
                                              float* __restrict__ dinv) {
  __shared__ int hist[CH];
  __shared__ int lrun[CH];
  __shared__ int sc[256];
  const int c = blockIdx.x, tid = threadIdx.x;
  const int e0 = cbase[c], e1 = cbase[c + 1];
  const int nv = e1 - e0;
  if (tid < CH) hist[tid] = 0;
  __syncthreads();
  for (int i = tid; i < nv; i += 256) atomicAdd(&hist[erec[e0 + i].y & (CH - 1)], 1);
  __syncthreads();
  int deg = (tid < CH) ? hist[tid] : 0;
  sc[tid] = deg;
  __syncthreads();
  for (int off = 1; off < 256; off <<= 1) {
    int val = (tid >= off) ? sc[tid - off] : 0;
    __syncthreads();
    sc[tid] += val;
    __syncthreads();
  }
  int excl = sc[tid] - deg;
  int node = c * CH + tid;
  if (tid < CH) {
    lrun[tid] = excl;
    if (node < NN) {
      rowptr[node] = e0 + excl;
      dinv[node] = rsqrtf((float)(deg + 1));  // in-degree + self loop
    } else if (node == NN) {
      rowptr[NN] = e0 + excl;  // == NE (last chunk)
    }
  }
  __syncthreads();
  for (int i = tid; i < nv; i += 256) {
    int2 r = erec[e0 + i];
    int pos = atomicAdd(&lrun[r.y & (CH - 1)], 1);
    esrc[e0 + pos] = r.x;
  }
}

// ---------------- MFMA GEMM1: xw1'[n] = dinv[n]*(x[n] @ W1), SLICED fp8 out ----------------
// Slice-major layout (verified in round 2): ushort at ((s*NN + n)*16 + m) holds
// features (s*16+m, s*16+m+64). Slice = 3.2 MB -> fits one XCD L2.

__global__ __launch_bounds__(256) void k_gemm_mfma(const float* __restrict__ A,
                                                   const unsigned short* __restrict__ Bp,
                                                   const float* __restrict__ dinv,
                                                   unsigned short* __restrict__ C) {
  constexpr int K = 128;
  constexpr int NCH = KF / 16;
  const int wv = blockIdx.x * 4 + (threadIdx.x >> 6);
  const int row0 = wv * 16;
  if (row0 >= NN) return;  // 100000 % 16 == 0
  const int lane = threadIdx.x & 63;
  const int m = lane & 15;
  const int q = lane >> 4;

  floatx4 acc[NCH];
#pragma unroll
  for (int i = 0; i < NCH; ++i) acc[i] = (floatx4){0.f, 0.f, 0.f, 0.f};

  const int arow = row0 + m;
#pragma unroll
  for (int kc = 0; kc < 4; ++kc) {
    const float* ap = A + (size_t)arow * K + kc * 32 + q * 8;
    float4 f0 = *(const float4*)ap;
    float4 f1 = *(const float4*)(ap + 4);
    short8 af;
    af[0] = (short)f2bf(f0.x); af[1] = (short)f2bf(f0.y);
    af[2] = (short)f2bf(f0.z); af[3] = (short)f2bf(f0.w);
    af[4] = (short)f2bf(f1.x); af[5] = (short)f2bf(f1.y);
    af[6] = (short)f2bf(f1.z); af[7] = (short)f2bf(f1.w);
    const unsigned short* bp = Bp + (size_t)kc * NCH * 512;
#pragma unroll
    for (int nc = 0; nc < NCH; ++nc) {
      short8 bfr = *(const short8*)(bp + (size_t)nc * 512 + lane * 8);
      acc[nc] = __builtin_amdgcn_mfma_f32_16x16x32_bf16(af, bfr, acc[nc], 0, 0, 0);
    }
  }

  float ds[4];
#pragma unroll
  for (int r = 0; r < 4; ++r) ds[r] = dinv[row0 + q * 4 + r];
#pragma unroll
  for (int nc = 0; nc < 4; ++nc) {
#pragma unroll
    for (int r = 0; r < 4; ++r) {
      int row = row0 + q * 4 + r;
      C[((size_t)nc * NN + row) * 16 + m] =
          pk_fp8(acc[nc][r] * ds[r], acc[nc + 4][r] * ds[r]);
    }
  }
}

// -------- XCD-pinned sliced aggregation --------
// blockIdx round-robins XCDs on MI355X (bid % 8 == XCD). slice = (bid%8)>>1 pins
// each 3.2 MB slice to 2 XCDs, whose L2 then holds it resident: compulsory FETCH
// drops from 8x12.8 MB (full replication) to 8x3.2 MB. One wave per (node, slice);
// lane e=lane>>3 serves edge sub-lane, d=lane&7 the dword (features s*16+2d,
// s*16+2d+64, s*16+2d+1, s*16+2d+65). 8 edges per wave-gather; tiers keep up to 8
// gathers in flight per lane; fold via 3 shfl_xor over e-groups.

#define SLICE_TIER(NJ)                                                 \
  for (; i + 8 * (NJ) <= r1; i += 8 * (NJ)) {                          \
    unsigned ss[NJ];                                                   \
    _Pragma("unroll") for (int j = 0; j < (NJ); ++j)                   \
        ss[j] = (unsigned)esrc[i + e + 8 * j];                         \
    unsigned vv[NJ];                                                   \
    _Pragma("unroll") for (int j = 0; j < (NJ); ++j)                   \
        vv[j] = pslice[(ss[j] << 3) + d];                              \
    _Pragma("unroll") for (int j = 0; j < (NJ); ++j) {                 \
      floatx2 lo = unpk_fp8((unsigned short)(vv[j] & 0xffffu));        \
      floatx2 hi = unpk_fp8((unsigned short)(vv[j] >> 16));            \
      a0 += lo.x; a1 += lo.y; a2 += hi.x; a3 += hi.y;                  \
    }                                                                  \
  }

// pass 1: h1'[n] = dinv[n]*relu( dinv[n]*(sum + self) + b1 ), sliced fp8 out
__global__ __launch_bounds__(128) void k_agg1(const unsigned short* __restrict__ p,
                                              const float* __restrict__ bias,
                                              const int* __restrict__ rowptr,
                                              const int* __restrict__ esrc,
                                              const float* __restrict__ dinv,
                                              unsigned short* __restrict__ outp) {
  const int bid = blockIdx.x;
  const int rr = bid & 7;
  const int s = rr >> 1;                 // slice, pinned to XCD pair
  const int n = (bid >> 3) * 4 + (rr & 1) * 2 + (threadIdx.x >> 6);
  const int lane = threadIdx.x & 63;
  const int e = lane >> 3;
  const int d = lane & 7;
  const unsigned* __restrict__ pslice = (const unsigned*)p + (size_t)s * NN * 8;

  float a0 = 0.f, a1 = 0.f, a2 = 0.f, a3 = 0.f;
  if (e == 0) {  // self term (prescaled), counted once
    unsigned v = pslice[((unsigned)n << 3) + d];
    floatx2 lo = unpk_fp8((unsigned short)(v & 0xffffu));
    floatx2 hi = unpk_fp8((unsigned short)(v >> 16));
    a0 = lo.x; a1 = lo.y; a2 = hi.x; a3 = hi.y;
  }

  const int r0 = rowptr[n];
  const int r1 = rowptr[n + 1];
  int i = r0;
  SLICE_TIER(8)   // 64 edges / iter, 8 gathers in flight per lane
  SLICE_TIER(4)
  SLICE_TIER(2)
  SLICE_TIER(1)
  if (i + e < r1) {  // tail < 8 edges
    unsigned ss = (unsigned)esrc[i + e];
    unsigned vv = pslice[(ss << 3) + d];
    floatx2 lo = unpk_fp8((unsigned short)(vv & 0xffffu));
    floatx2 hi = unpk_fp8((unsigned short)(vv >> 16));
    a0 += lo.x; a1 += lo.y; a2 += hi.x; a3 += hi.y;
  }

  a0 += __shfl_xor(a0, 8, 64);  a1 += __shfl_xor(a1, 8, 64);
  a2 += __shfl_xor(a2, 8, 64);  a3 += __shfl_xor(a3, 8, 64);
  a0 += __shfl_xor(a0, 16, 64); a1 += __shfl_xor(a1, 16, 64);
  a2 += __shfl_xor(a2, 16, 64); a3 += __shfl_xor(a3, 16, 64);
  a0 += __shfl_xor(a0, 32, 64); a1 += __shfl_xor(a1, 32, 64);
  a2 += __shfl_xor(a2, 32, 64); a3 += __shfl_xor(a3, 32, 64);

  if (e == 0) {
    const float dn = dinv[n];
    const int tb = s * 16 + 2 * d;
    float2 blo = *(const float2*)(bias + tb);       // bias[tb], bias[tb+1]
    float2 bhi = *(const float2*)(bias + tb + 64);  // bias[tb+64], bias[tb+65]
    float x0 = fmaxf(fmaf(dn, a0, blo.x), 0.f) * dn;   // feat tb
    float x1 = fmaxf(fmaf(dn, a1, bhi.x), 0.f) * dn;   // feat tb+64
    float x2 = fmaxf(fmaf(dn, a2, blo.y), 0.f) * dn;   // feat tb+1
    float x3 = fmaxf(fmaf(dn, a3, bhi.y), 0.f) * dn;   // feat tb+65
    unsigned lo = pk_fp8(x0, x1);
    unsigned hi = pk_fp8(x2, x3);
    ((unsigned*)outp)[(size_t)s * NN * 8 + ((unsigned)n << 3) + d] = lo | (hi << 16);
  }
}

// pass 2: pooled[batch[n]] += dinv[n]*(sum + self), fp32 atomics (256 KB, L2-hot)
__global__ __launch_bounds__(128) void k_aggpool(const unsigned short* __restrict__ p,
                                                 const int* __restrict__ batch,
                                                 const int* __restrict__ rowptr,
                                                 const int* __restrict__ esrc,
                                                 const float* __restrict__ dinv,
                                                 float* __restrict__ pooled) {
  const int bid = blockIdx.x;
  const int rr = bid & 7;
  const int s = rr >> 1;
  const int n = (bid >> 3) * 4 + (rr & 1) * 2 + (threadIdx.x >> 6);
  const int lane = threadIdx.x & 63;
  const int e = lane >> 3;
  const int d = lane & 7;
  const unsigned* __restrict__ pslice = (const unsigned*)p + (size_t)s * NN * 8;

  float a0 = 0.f, a1 = 0.f, a2 = 0.f, a3 = 0.f;
  if (e == 0) {  // self term
    unsigned v = pslice[((unsigned)n << 3) + d];
    floatx2 lo = unpk_fp8((unsigned short)(v & 0xffffu));
    floatx2 hi = unpk_fp8((unsigned short)(v >> 16));
    a0 = lo.x; a1 = lo.y; a2 = hi.x; a3 = hi.y;
  }

  const int r0 = rowptr[n];
  const int r1 = rowptr[n + 1];
  int i = r0;
  SLICE_TIER(8)
  SLICE_TIER(4)
  SLICE_TIER(2)
  SLICE_TIER(1)
  if (i + e < r1) {
    unsigned ss = (unsigned)esrc[i + e];
    unsigned vv = pslice[(ss << 3) + d];
    floatx2 lo = unpk_fp8((unsigned short)(vv & 0xffffu));
    floatx2 hi = unpk_fp8((unsigned short)(vv >> 16));
    a0 += lo.x; a1 += lo.y; a2 += hi.x; a3 += hi.y;
  }

  a0 += __shfl_xor(a0, 8, 64);  a1 += __shfl_xor(a1, 8, 64);
  a2 += __shfl_xor(a2, 8, 64);  a3 += __shfl_xor(a3, 8, 64);
  a0 += __shfl_xor(a0, 16, 64); a1 += __shfl_xor(a1, 16, 64);
  a2 += __shfl_xor(a2, 16, 64); a3 += __shfl_xor(a3, 16, 64);
  a0 += __shfl_xor(a0, 32, 64); a1 += __shfl_xor(a1, 32, 64);
  a2 += __shfl_xor(a2, 32, 64); a3 += __shfl_xor(a3, 32, 64);

  if (e == 0) {
    const float dn = dinv[n];
    const int g = batch[n];
    const int tb = s * 16 + 2 * d;
    float* base = pooled + (size_t)g * KF;
    atomicAdd(base + tb,      dn * a0);
    atomicAdd(base + tb + 64, dn * a1);
    atomicAdd(base + tb + 1,  dn * a2);
    atomicAdd(base + tb + 65, dn * a3);
  }
}

#undef SLICE_TIER

// ---------------- heads: mean + W2 GEMM + group/family heads (one block per graph) -------------

__global__ __launch_bounds__(256) void k_heads(const float* __restrict__ pooled,
                                               const int* __restrict__ gb,
                                               const float* __restrict__ W2,
                                               const float* __restrict__ b2,
                                               const float* __restrict__ Wg,
                                               const float* __restrict__ bg,
                                               const float* __restrict__ Wf,
                                               const float* __restrict__ bfb,
                                               float* __restrict__ out) {
  __shared__ float pr[KF];
  __shared__ float pp[H2F];
  const int g = blockIdx.x;
  const int tid = threadIdx.x;
  if (tid < KF) {
    float c = fmaxf((float)(gb[g + 1] - gb[g]), 1.f);
    pr[tid] = pooled[(size_t)g * KF + tid] / c;
  }
  __syncthreads();
  float acc = b2[tid];
#pragma unroll 8
  for (int d = 0; d < KF; ++d) acc = fmaf(pr[d], W2[d * H2F + tid], acc);
  pp[tid] = acc;
  __syncthreads();
  if (tid < NGRP) {
    float a = bg[tid];
    for (int d = 0; d < H2F; ++d) a = fmaf(pp[d], Wg[d * NGRP + tid], a);
    out[g * NGRP + tid] = a;
  } else if (tid >= 64 && tid < 64 + NGRP * NFAM) {
    int uu = tid - 64;
    int gg = uu / NFAM;
    int ff = uu % NFAM;
    float a = bfb[gg * NFAM + ff];
    for (int d = 0; d < H2F; ++d) a = fmaf(pp[d], Wf[(gg * H2F + d) * NFAM + ff], a);
    out[NGR * NGRP + (size_t)gg * NGR * NFAM + g * NFAM + ff] = a;
  }
}

// ---------------- launch ----------------

extern "C" void kernel_launch(void* const* d_in, const int* in_sizes, int n_in,
                              void* d_out, int out_size, void* d_ws, size_t ws_size,
                              hipStream_t stream) {
  const float* x    = (const float*)d_in[0];
  const int*   ei   = (const int*)d_in[1];
  const int*   batch= (const int*)d_in[2];
  const float* W1   = (const float*)d_in[3];
  const float* b1   = (const float*)d_in[4];
  const float* W2   = (const float*)d_in[5];
  const float* b2   = (const float*)d_in[6];
  const float* Wg   = (const float*)d_in[7];
  const float* bg   = (const float*)d_in[8];
  const float* Wf   = (const float*)d_in[9];
  const float* bfb  = (const float*)d_in[10];
  float* out = (float*)d_out;

  char* w = (char*)d_ws;
  auto take = [&](size_t bytes) {
    char* p = w;
    w += (bytes + 255) & ~(size_t)255;
    return (void*)p;
  };
  int*   tot   = (int*)take((size_t)NCHUNK * 4);
  float* pooled= (float*)take((size_t)NGR * KF * 4);  // adjacent to tot: one memset covers both
  int*   gb    = (int*)take((size_t)(NGR + 1) * 4);   // fully written by histprep's gb branch
  int*   cbase = (int*)take((size_t)(NCHUNK + 1) * 4);
  int*   cursor= (int*)take((size_t)NCHUNK * 4);
  int2*  erec  = (int2*)take((size_t)NE * 8);
  int*   esrc  = (int*)take((size_t)NE * 4);
  int*   rowptr= (int*)take((size_t)(NN + 1) * 4);
  float* dinv  = (float*)take((size_t)NN * 4);
  unsigned short* Bp1 = (unsigned short*)take((size_t)KF * KF * 2);
  unsigned short* xw1 = (unsigned short*)take((size_t)NN * 64 * 2);  // sliced fp8 pairs
  unsigned short* h1  = (unsigned short*)take((size_t)NN * 64 * 2);  // sliced fp8 pairs

  // zero tot + pooled in one shot (adjacent in workspace)
  size_t zbytes = (size_t)((char*)pooled - (char*)tot) + (size_t)NGR * KF * 4;
  hipMemsetAsync(tot, 0, zbytes, stream);

  k_histprep<<<NT + PREPB_BLKS + GBB, 256, 0, stream>>>(ei, batch, tot, gb, W1, Bp1);
  k_scantot<<<1, 256, 0, stream>>>(tot, cbase, cursor);
  k_pscatter<<<NT, 256, 0, stream>>>(ei, cursor, erec);
  k_sort<<<NCHUNK, 256, 0, stream>>>(erec, cbase, esrc, rowptr, dinv);

  k_gemm_mfma<<<1563, 256, 0, stream>>>(x, Bp1, dinv, xw1);

  k_agg1<<<(NN / 4) * 8, 128, 0, stream>>>(xw1, b1, rowptr, esrc, dinv, h1);
  k_aggpool<<<(NN / 4) * 8, 128, 0, stream>>>(h1, batch, rowptr, esrc, dinv, pooled);
  k_heads<<<NGR, 256, 0, stream>>>(pooled, gb, W2, b2, Wg, bg, Wf, bfb, out);
}

// Round 13
// 292.135 us; speedup vs baseline: 1.9916x; 1.9916x over previous
//
#include <hip/hip_runtime.h>

#define NN 100000     // nodes
#define NE 1600000    // edges
#define NGR 512       // graphs
#define KF 128        // IN_F == H1
#define H2F 256
#define NGRP 16
#define NFAM 10

#define CH 128                          // nodes per chunk
#define NCHUNK ((NN + CH - 1) / CH)     // 782
#define PT 6656                         // edges per partition tile (round-1 best)
#define NT ((NE + PT - 1) / PT)         // 241
#define PREPB_BLKS 64                   // 128*128/256
#define GBB ((NN + 255) / 256)          // 391 blocks: graph-boundary scan

#define NSPLIT 8                        // blocks per graph for fused conv2+pool
#define SRCMASK 0x1FFFF                 // 17 bits: NN=100000 < 131072

typedef __attribute__((ext_vector_type(8))) short short8;
typedef __attribute__((ext_vector_type(4))) float floatx4;
typedef __attribute__((ext_vector_type(2))) float floatx2;

__device__ __forceinline__ unsigned short f2bf(float f) {
  unsigned u = __float_as_uint(f);
  unsigned r = (u + 0x7fff + ((u >> 16) & 1)) >> 16;
  return (unsigned short)r;
}
// fp8 e4m3 pair (features t, t+64) <-> floats via gfx950 HW converters
__device__ __forceinline__ unsigned short pk_fp8(float a, float b) {
  return (unsigned short)__builtin_amdgcn_cvt_pk_fp8_f32(a, b, 0, false);
}
__device__ __forceinline__ floatx2 unpk_fp8(unsigned short u) {
  return __builtin_amdgcn_cvt_pk_f32_fp8((int)u, false);
}

// ------- merged: per-tile chunk histogram -> tot | W1 swizzle | graph-boundary scan -------

__global__ __launch_bounds__(256) void k_histprep(const int* __restrict__ ei,
                                                  const int* __restrict__ batch,
                                                  int* __restrict__ tot,
                                                  int* __restrict__ gb,
                                                  const float* __restrict__ W,
                                                  unsigned short* __restrict__ Bp) {
  __shared__ int lh[NCHUNK];
  int tid = threadIdx.x;
  if (blockIdx.x >= NT + PREPB_BLKS) {  // graph-boundary scan
    int n = (blockIdx.x - NT - PREPB_BLKS) * 256 + tid;
    if (n >= NN) return;
    int b0 = batch[n];
    if (n == 0) {
      for (int g = 0; g <= b0; ++g) gb[g] = 0;
    }
    int b1 = (n + 1 < NN) ? batch[n + 1] : NGR;
    for (int g = b0 + 1; g <= b1; ++g) gb[g] = n + 1;
    return;
  }
  if (blockIdx.x >= NT) {  // W1 swizzle
    int idx = (blockIdx.x - NT) * 256 + tid;
    int j = idx & 7;
    int l = (idx >> 3) & 63;
    int rest = idx >> 9;
    int nc = rest & 7;
    int kc = rest >> 3;
    int k = kc * 32 + (l >> 4) * 8 + j;
    int nn = nc * 16 + (l & 15);
    Bp[idx] = f2bf(W[k * KF + nn]);
    return;
  }
  for (int g = tid; g < NCHUNK; g += 256) lh[g] = 0;
  __syncthreads();
  int base = blockIdx.x * PT;
  int nv = min(PT, NE - base);
  for (int i = tid; i < nv; i += 256) atomicAdd(&lh[ei[NE + base + i] >> 7], 1);
  __syncthreads();
  for (int g = tid; g < NCHUNK; g += 256) {
    int v = lh[g];
    if (v) atomicAdd(&tot[g], v);
  }
}

// ---------------- exclusive scan tot -> cbase; init cursor ----------------

__global__ __launch_bounds__(256) void k_scantot(const int* __restrict__ tot,
                                                 int* __restrict__ cbase,
                                                 int* __restrict__ cursor) {
  __shared__ int ssc[256];
  int tid = threadIdx.x;
  int v4[4]; int loc = 0;
#pragma unroll
  for (int j = 0; j < 4; ++j) {
    int idx = tid * 4 + j;
    v4[j] = (idx < NCHUNK) ? tot[idx] : 0;
    loc += v4[j];
  }
  ssc[tid] = loc;
  __syncthreads();
  for (int off = 1; off < 256; off <<= 1) {
    int val = (tid >= off) ? ssc[tid - off] : 0;
    __syncthreads();
    ssc[tid] += val;
    __syncthreads();
  }
  int excl = ssc[tid] - loc;
#pragma unroll
  for (int j = 0; j < 4; ++j) {
    int idx = tid * 4 + j;
    if (idx < NCHUNK) { cbase[idx] = excl; cursor[idx] = excl; }
    excl += v4[j];
  }
  if (tid == 255) cbase[NCHUNK] = excl;  // == NE
}

// ---------------- partition: LDS-staged, cursor-reserved per-chunk slices ----------------
// PACKED erec: int = (local_dst<<17) | src  (chunk id implicit in position — sort
// block c consumes exactly chunk c's range). Halves erec traffic + LDS stage.

__global__ __launch_bounds__(256) void k_pscatter(const int* __restrict__ ei,
                                                  int* __restrict__ cursor,
                                                  int* __restrict__ erec) {
  __shared__ int stage[PT];
  __shared__ unsigned short stagec[PT];   // chunk id (10 bits) per staged edge
  __shared__ int lstart[NCHUNK];
  __shared__ int lrun[NCHUNK];
  __shared__ int gbase[NCHUNK];
  __shared__ int ssc[256];
  int t0 = blockIdx.x, tid = threadIdx.x;
  for (int g = tid; g < NCHUNK; g += 256) lrun[g] = 0;
  __syncthreads();
  int base = t0 * PT;
  int nv = min(PT, NE - base);
  for (int i = tid; i < nv; i += 256) atomicAdd(&lrun[ei[NE + base + i] >> 7], 1);
  __syncthreads();
  int v4[4]; int loc = 0;
#pragma unroll
  for (int j = 0; j < 4; ++j) {
    int idx = tid * 4 + j;
    v4[j] = (idx < NCHUNK) ? lrun[idx] : 0;
    loc += v4[j];
  }
  ssc[tid] = loc;
  __syncthreads();
  for (int off = 1; off < 256; off <<= 1) {
    int val = (tid >= off) ? ssc[tid - off] : 0;
    __syncthreads();
    ssc[tid] += val;
    __syncthreads();
  }
  int excl = ssc[tid] - loc;
#pragma unroll
  for (int j = 0; j < 4; ++j) {
    int idx = tid * 4 + j;
    if (idx < NCHUNK) lstart[idx] = excl;
    excl += v4[j];
  }
  __syncthreads();
  for (int g = tid; g < NCHUNK; g += 256) {
    int cnt = ((g + 1 < NCHUNK) ? lstart[g + 1] : nv) - lstart[g];
    gbase[g] = cnt ? atomicAdd(&cursor[g], cnt) : 0;
    lrun[g] = lstart[g];
  }
  __syncthreads();
  for (int i = tid; i < nv; i += 256) {
    int s = ei[base + i], d = ei[NE + base + i];
    int g = d >> 7;
    int pos = atomicAdd(&lrun[g], 1);
    stage[pos] = ((d & (CH - 1)) << 17) | s;
    stagec[pos] = (unsigned short)g;
  }
  __syncthreads();
  for (int j = tid; j < nv; j += 256) {
    int g = stagec[j];
    erec[gbase[g] + (j - lstart[g])] = stage[j];
  }
}

// ---------------- per-chunk counting sort into packed per-node runs (+dinv) ----------------

__global__ __launch_bounds__(256) void k_sort(const int* __restrict__ erec,
                                              const int* __restrict__ cbase,
                                              int* __restrict__ esrc,
                                              int* __restrict__ rowptr,
                                              float* __restrict__ dinv) {
  __shared__ int hist[CH];
  __shared__ int lrun[CH];
  __shared__ int sc[256];
  const int c = blockIdx.x, tid = threadIdx.x;
  const int e0 = cbase[c], e1 = cbase[c + 1];
  const int nv = e1 - e0;
  if (tid < CH) hist[tid] = 0;
  __syncthreads();
  for (int i = tid; i < nv; i += 256) atomicAdd(&hist[(erec[e0 + i] >> 17) & (CH - 1)], 1);
  __syncthreads();
  int deg = (tid < CH) ? hist[tid] : 0;
  sc[tid] = deg;
  __syncthreads();
  for (int off = 1; off < 256; off <<= 1) {
    int val = (tid >= off) ? sc[tid - off] : 0;
    __syncthreads();
    sc[tid] += val;
    __syncthreads();
  }
  int excl = sc[tid] - deg;
  int node = c * CH + tid;
  if (tid < CH) {
    lrun[tid] = excl;
    if (node < NN) {
      rowptr[node] = e0 + excl;
      dinv[node] = rsqrtf((float)(deg + 1));  // in-degree + self loop
    } else if (node == NN) {
      rowptr[NN] = e0 + excl;  // == NE (last chunk)
    }
  }
  __syncthreads();
  for (int i = tid; i < nv; i += 256) {
    int r = erec[e0 + i];
    int pos = atomicAdd(&lrun[(r >> 17) & (CH - 1)], 1);
    esrc[e0 + pos] = r & SRCMASK;
  }
}

// ---------------- MFMA GEMM1: xw1'[n] = dinv[n]*(x[n] @ W1), fp8 out ----------------
// fp8 row layout: ushort at pos t holds features (t, t+64); in C-layout these are
// cols nc*16+m and (nc+4)*16+m -- SAME lane, so packing is lane-local.

__global__ __launch_bounds__(256) void k_gemm_mfma(const float* __restrict__ A,
                                                   const unsigned short* __restrict__ Bp,
                                                   const float* __restrict__ dinv,
                                                   unsigned short* __restrict__ C) {
  constexpr int K = 128;
  constexpr int NCH = KF / 16;
  const int wv = blockIdx.x * 4 + (threadIdx.x >> 6);
  const int row0 = wv * 16;
  if (row0 >= NN) return;  // 100000 % 16 == 0
  const int lane = threadIdx.x & 63;
  const int m = lane & 15;
  const int q = lane >> 4;

  floatx4 acc[NCH];
#pragma unroll
  for (int i = 0; i < NCH; ++i) acc[i] = (floatx4){0.f, 0.f, 0.f, 0.f};

  const int arow = row0 + m;
#pragma unroll
  for (int kc = 0; kc < 4; ++kc) {
    const float* ap = A + (size_t)arow * K + kc * 32 + q * 8;
    float4 f0 = *(const float4*)ap;
    float4 f1 = *(const float4*)(ap + 4);
    short8 af;
    af[0] = (short)f2bf(f0.x); af[1] = (short)f2bf(f0.y);
    af[2] = (short)f2bf(f0.z); af[3] = (short)f2bf(f0.w);
    af[4] = (short)f2bf(f1.x); af[5] = (short)f2bf(f1.y);
    af[6] = (short)f2bf(f1.z); af[7] = (short)f2bf(f1.w);
    const unsigned short* bp = Bp + (size_t)kc * NCH * 512;
#pragma unroll
    for (int nc = 0; nc < NCH; ++nc) {
      short8 bfr = *(const short8*)(bp + (size_t)nc * 512 + lane * 8);
      acc[nc] = __builtin_amdgcn_mfma_f32_16x16x32_bf16(af, bfr, acc[nc], 0, 0, 0);
    }
  }

  float ds[4];
#pragma unroll
  for (int r = 0; r < 4; ++r) ds[r] = dinv[row0 + q * 4 + r];
#pragma unroll
  for (int nc = 0; nc < 4; ++nc) {
#pragma unroll
    for (int r = 0; r < 4; ++r) {
      int row = row0 + q * 4 + r;
      C[(size_t)row * 64 + nc * 16 + m] =
          pk_fp8(acc[nc][r] * ds[r], acc[nc + 4][r] * ds[r]);
    }
  }
}

// ---------------- aggregation pass 1: paired-edge dword gathers (round-1 form) ----------------
// Row = 128 B = 32 dwords. Lanes 0-31 process even-offset edges, lanes 32-63
// odd-offset edges; each lane loads one dword = fp8 pairs for features
// (2u, 2u+64) and (2u+1, 2u+65). Halves fold via __shfl_down(.,32).
// h1'[n] = dinv[n]*relu( dinv[n]*(sum + self) + b1 ), fp8 out

__global__ __launch_bounds__(128) void k_agg1(const unsigned short* __restrict__ p,
                                              const float* __restrict__ bias,
                                              const int* __restrict__ rowptr,
                                              const int* __restrict__ esrc,
                                              const float* __restrict__ dinv,
                                              unsigned short* __restrict__ outp) {
  const int n = blockIdx.x * 2 + (threadIdx.x >> 6);
  const int t = threadIdx.x & 63;
  const int u = t & 31;      // dword index within the 32-dword row
  const int half = t >> 5;   // which edge of the pair this lane serves
  const unsigned* __restrict__ prow = (const unsigned*)p;

  // accumulators for features 2u, 2u+64, 2u+1, 2u+65
  float a0 = 0.f, a1 = 0.f, a2 = 0.f, a3 = 0.f;

  if (half == 0) {  // self term (prescaled input), added once
    unsigned v = prow[((unsigned)n << 5) + u];
    floatx2 lo = unpk_fp8((unsigned short)(v & 0xffffu));
    floatx2 hi = unpk_fp8((unsigned short)(v >> 16));
    a0 = lo.x; a1 = lo.y; a2 = hi.x; a3 = hi.y;
  }

  const int r0 = rowptr[n];
  const int r1 = rowptr[n + 1];
  int i = r0;

#define PAIR_TIER(NP)                                                  \
  for (; i + 2 * (NP) <= r1; i += 2 * (NP)) {                          \
    const int ib = i + half;                                           \
    unsigned s[NP];                                                    \
    _Pragma("unroll") for (int j = 0; j < (NP); ++j)                   \
        s[j] = (unsigned)esrc[ib + 2 * j];                             \
    unsigned v[NP];                                                    \
    _Pragma("unroll") for (int j = 0; j < (NP); ++j)                   \
        v[j] = prow[(s[j] << 5) + u];                                  \
    _Pragma("unroll") for (int j = 0; j < (NP); ++j) {                 \
      floatx2 lo = unpk_fp8((unsigned short)(v[j] & 0xffffu));         \
      floatx2 hi = unpk_fp8((unsigned short)(v[j] >> 16));             \
      a0 += lo.x; a1 += lo.y; a2 += hi.x; a3 += hi.y;                  \
    }                                                                  \
  }

  PAIR_TIER(8)   // 16 edges / iter
  PAIR_TIER(4)   // 8
  PAIR_TIER(2)   // 4
  PAIR_TIER(1)   // 2
#undef PAIR_TIER

  if (i < r1 && half == 0) {  // odd leftover edge: half 0 only
    unsigned s = (unsigned)esrc[i];
    unsigned v = prow[(s << 5) + u];
    floatx2 lo = unpk_fp8((unsigned short)(v & 0xffffu));
    floatx2 hi = unpk_fp8((unsigned short)(v >> 16));
    a0 += lo.x; a1 += lo.y; a2 += hi.x; a3 += hi.y;
  }

  // fold half-wave partials: lane u gets lane u+32's sums
  a0 += __shfl_down(a0, 32, 64);
  a1 += __shfl_down(a1, 32, 64);
  a2 += __shfl_down(a2, 32, 64);
  a3 += __shfl_down(a3, 32, 64);

  if (half == 0) {
    const float dn = dinv[n];
    float2 blo = *(const float2*)(bias + 2 * u);       // bias[2u], bias[2u+1]
    float2 bhi = *(const float2*)(bias + 64 + 2 * u);  // bias[2u+64], bias[2u+65]
    float x0 = fmaxf(fmaf(dn, a0, blo.x), 0.f) * dn;   // feat 2u
    float x1 = fmaxf(fmaf(dn, a1, bhi.x), 0.f) * dn;   // feat 2u+64
    float x2 = fmaxf(fmaf(dn, a2, blo.y), 0.f) * dn;   // feat 2u+1
    float x3 = fmaxf(fmaf(dn, a3, bhi.y), 0.f) * dn;   // feat 2u+65
    unsigned lo = pk_fp8(x0, x1);
    unsigned hi = pk_fp8(x2, x3);
    ((unsigned*)outp)[((unsigned)n << 5) + u] = lo | (hi << 16);
  }
}

// ---------------- fused conv2 + partial mean-pool (NSPLIT blocks per graph) ----------------
// NODE-sliced: part p of graph g handles nodes [ns,ne). Per node, the wave
// accumulates the run-sum with agg1's PAIR_TIER structure (self row included via
// half==0), then folds with ONE fmaf by dn = dinv[n]. Partial 128-float pooled
// sums are LDS-reduced and atomicAdd'ed into pooled[g]. Bounds from gb[].

__global__ __launch_bounds__(256) void k_aggpart(const unsigned short* __restrict__ p,
                                                 const int* __restrict__ gb,
                                                 const int* __restrict__ rowptr,
                                                 const int* __restrict__ esrc,
                                                 const float* __restrict__ dinv,
                                                 float* __restrict__ pooled) {
  __shared__ float sacc[4][128];
  const int g = blockIdx.x / NSPLIT;
  const int part = blockIdx.x % NSPLIT;
  const int tid = threadIdx.x;
  const int start = gb[g], end = gb[g + 1];
  const int wv = tid >> 6, t = tid & 63, u = t & 31, half = t >> 5;
  const unsigned* __restrict__ prow = (const unsigned*)p;

  float a0 = 0.f, a1 = 0.f, a2 = 0.f, a3 = 0.f;

  const int nlen = end - start;
  const int nper = (nlen + NSPLIT - 1) / NSPLIT;
  const int ns = min(start + part * nper, end);
  const int ne = min(ns + nper, end);

  for (int n = ns + wv; n < ne; n += 4) {
    float t0, t1, t2, t3;
    if (half == 0) {  // self row, counted once
      unsigned v = prow[((unsigned)n << 5) + u];
      floatx2 lo = unpk_fp8((unsigned short)(v & 0xffffu));
      floatx2 hi = unpk_fp8((unsigned short)(v >> 16));
      t0 = lo.x; t1 = lo.y; t2 = hi.x; t3 = hi.y;
    } else {
      t0 = 0.f; t1 = 0.f; t2 = 0.f; t3 = 0.f;
    }
    const int r0 = rowptr[n];
    const int r1 = rowptr[n + 1];
    int i = r0;

#define PAIR_TIER(NP)                                                  \
    for (; i + 2 * (NP) <= r1; i += 2 * (NP)) {                        \
      const int ib = i + half;                                         \
      unsigned s[NP];                                                  \
      _Pragma("unroll") for (int j = 0; j < (NP); ++j)                 \
          s[j] = (unsigned)esrc[ib + 2 * j];                           \
      unsigned v[NP];                                                  \
      _Pragma("unroll") for (int j = 0; j < (NP); ++j)                 \
          v[j] = prow[(s[j] << 5) + u];                                \
      _Pragma("unroll") for (int j = 0; j < (NP); ++j) {               \
        floatx2 lo = unpk_fp8((unsigned short)(v[j] & 0xffffu));       \
        floatx2 hi = unpk_fp8((unsigned short)(v[j] >> 16));           \
        t0 += lo.x; t1 += lo.y; t2 += hi.x; t3 += hi.y;                \
      }                                                                \
    }

    PAIR_TIER(8)   // 16 edges / iter
    PAIR_TIER(4)   // 8
    PAIR_TIER(2)   // 4
    PAIR_TIER(1)   // 2
#undef PAIR_TIER

    if (i < r1 && half == 0) {  // odd leftover edge
      unsigned s = (unsigned)esrc[i];
      unsigned v = prow[(s << 5) + u];
      floatx2 lo = unpk_fp8((unsigned short)(v & 0xffffu));
      floatx2 hi = unpk_fp8((unsigned short)(v >> 16));
      t0 += lo.x; t1 += lo.y; t2 += hi.x; t3 += hi.y;
    }

    const float dn = dinv[n];
    a0 = fmaf(dn, t0, a0); a1 = fmaf(dn, t1, a1);
    a2 = fmaf(dn, t2, a2); a3 = fmaf(dn, t3, a3);
  }

  // fold half-wave partials
  a0 += __shfl_down(a0, 32, 64);
  a1 += __shfl_down(a1, 32, 64);
  a2 += __shfl_down(a2, 32, 64);
  a3 += __shfl_down(a3, 32, 64);
  if (half == 0) {
    sacc[wv][2 * u] = a0;       // feat 2u
    sacc[wv][2 * u + 1] = a2;   // feat 2u+1
    sacc[wv][2 * u + 64] = a1;  // feat 2u+64
    sacc[wv][2 * u + 65] = a3;  // feat 2u+65
  }
  __syncthreads();
  if (tid < KF) {
    float v = sacc[0][tid] + sacc[1][tid] + sacc[2][tid] + sacc[3][tid];
    atomicAdd(&pooled[(size_t)g * KF + tid], v);
  }
}

// ---------------- heads: mean + W2 GEMM + group/family heads (one block per graph) -------------

__global__ __launch_bounds__(256) void k_heads(const float* __restrict__ pooled,
                                               const int* __restrict__ gb,
                                               const float* __restrict__ W2,
                                               const float* __restrict__ b2,
                                               const float* __restrict__ Wg,
                                               const float* __restrict__ bg,
                                               const float* __restrict__ Wf,
                                               const float* __restrict__ bfb,
                                               float* __restrict__ out) {
  __shared__ float pr[KF];
  __shared__ float pp[H2F];
  const int g = blockIdx.x;
  const int tid = threadIdx.x;
  if (tid < KF) {
    float c = fmaxf((float)(gb[g + 1] - gb[g]), 1.f);
    pr[tid] = pooled[(size_t)g * KF + tid] / c;
  }
  __syncthreads();
  float acc = b2[tid];
#pragma unroll 8
  for (int d = 0; d < KF; ++d) acc = fmaf(pr[d], W2[d * H2F + tid], acc);
  pp[tid] = acc;
  __syncthreads();
  if (tid < NGRP) {
    float a = bg[tid];
    for (int d = 0; d < H2F; ++d) a = fmaf(pp[d], Wg[d * NGRP + tid], a);
    out[g * NGRP + tid] = a;
  } else if (tid >= 64 && tid < 64 + NGRP * NFAM) {
    int uu = tid - 64;
    int gg = uu / NFAM;
    int ff = uu % NFAM;
    float a = bfb[gg * NFAM + ff];
    for (int d = 0; d < H2F; ++d) a = fmaf(pp[d], Wf[(gg * H2F + d) * NFAM + ff], a);
    out[NGR * NGRP + (size_t)gg * NGR * NFAM + g * NFAM + ff] = a;
  }
}

// ---------------- launch ----------------

extern "C" void kernel_launch(void* const* d_in, const int* in_sizes, int n_in,
                              void* d_out, int out_size, void* d_ws, size_t ws_size,
                              hipStream_t stream) {
  const float* x    = (const float*)d_in[0];
  const int*   ei   = (const int*)d_in[1];
  const int*   batch= (const int*)d_in[2];
  const float* W1   = (const float*)d_in[3];
  const float* b1   = (const float*)d_in[4];
  const float* W2   = (const float*)d_in[5];
  const float* b2   = (const float*)d_in[6];
  const float* Wg   = (const float*)d_in[7];
  const float* bg   = (const float*)d_in[8];
  const float* Wf   = (const float*)d_in[9];
  const float* bfb  = (const float*)d_in[10];
  float* out = (float*)d_out;

  char* w = (char*)d_ws;
  auto take = [&](size_t bytes) {
    char* p = w;
    w += (bytes + 255) & ~(size_t)255;
    return (void*)p;
  };
  int*   tot   = (int*)take((size_t)NCHUNK * 4);
  float* pooled= (float*)take((size_t)NGR * KF * 4);  // adjacent to tot: one memset covers both
  int*   gb    = (int*)take((size_t)(NGR + 1) * 4);   // fully written by histprep's gb branch
  int*   cbase = (int*)take((size_t)(NCHUNK + 1) * 4);
  int*   cursor= (int*)take((size_t)NCHUNK * 4);
  int*   erec  = (int*)take((size_t)NE * 4);          // packed (local_dst<<17)|src
  int*   esrc  = (int*)take((size_t)NE * 4);
  int*   rowptr= (int*)take((size_t)(NN + 1) * 4);
  float* dinv  = (float*)take((size_t)NN * 4);
  unsigned short* Bp1 = (unsigned short*)take((size_t)KF * KF * 2);
  unsigned short* xw1 = (unsigned short*)take((size_t)NN * 64 * 2);  // fp8 pairs
  unsigned short* h1  = (unsigned short*)take((size_t)NN * 64 * 2);  // fp8 pairs

  // zero tot + pooled in one shot (adjacent in workspace)
  size_t zbytes = (size_t)((char*)pooled - (char*)tot) + (size_t)NGR * KF * 4;
  hipMemsetAsync(tot, 0, zbytes, stream);

  k_histprep<<<NT + PREPB_BLKS + GBB, 256, 0, stream>>>(ei, batch, tot, gb, W1, Bp1);
  k_scantot<<<1, 256, 0, stream>>>(tot, cbase, cursor);
  k_pscatter<<<NT, 256, 0, stream>>>(ei, cursor, erec);
  k_sort<<<NCHUNK, 256, 0, stream>>>(erec, cbase, esrc, rowptr, dinv);

  k_gemm_mfma<<<1563, 256, 0, stream>>>(x, Bp1, dinv, xw1);

  k_agg1<<<NN / 2, 128, 0, stream>>>(xw1, b1, rowptr, esrc, dinv, h1);
  k_aggpart<<<NGR * NSPLIT, 256, 0, stream>>>(h1, gb, rowptr, esrc, dinv, pooled);
  k_heads<<<NGR, 256, 0, stream>>>(pooled, gb, W2, b2, Wg, bg, Wf, bfb, out);
}